// Round 5
// baseline (167.452 us; speedup 1.0000x reference)
//
#include <hip/hip_runtime.h>

// ---------------------------------------------------------------------------
// IntraAgg: neighbor top-S + train-pos top-P aggregation + concat + GEMM+ReLU
// B=8192, K=64 (S=33), Ppool=2048 (P=33), D=128, Dout=128. All f32.
// ws layout: [cat: B*2D f32][sorted pool vals: Ppool f32][sorted pool gidx: Ppool i32]
// Fixed ~100us of dur_us is harness reset dispatches (measured across rounds 1/3/4);
// controllable kernel time this round: row ~49 -> target ~22, gemm ~8, sort ~3.
// ---------------------------------------------------------------------------

// Kernel 0 v3 (unchanged, dropped out of top-5): one WAVE per pool element.
__global__ __launch_bounds__(256) void sort_pool_kernel(
    const float* __restrict__ tp_logits,   // [Ppool][2]
    const int*   __restrict__ tp_idx,      // [Ppool]
    float* __restrict__ sv,                // out: sorted values [Ppool]
    int*   __restrict__ sg,                // out: feature row idx in sorted order
    int Ppool)
{
    __shared__ float v[2048];
    const int t = threadIdx.x;
    const float2* tp2 = (const float2*)tp_logits;
    const bool useL = (Ppool <= 2048);
    if (useL) {
        for (int j = t; j < Ppool; j += 256) v[j] = tp2[j].x;
        __syncthreads();
    }
    const int lane = t & 63;
    const int i = blockIdx.x * 4 + (t >> 6);
    if (i >= Ppool) return;
    const float vi = useL ? v[i] : tp2[i].x;
    int r = 0;
    for (int j = lane; j < Ppool; j += 64) {
        float vj = useL ? v[j] : tp2[j].x;
        r += (int)((vj < vi) | ((vj == vi) & (j < i)));   // total order -> distinct ranks
    }
#pragma unroll
    for (int off = 32; off > 0; off >>= 1) r += __shfl_down(r, off);
    if (lane == 0) { sv[r] = vi; sg[r] = tp_idx[i]; }
}

// Kernel 1 v4: ONE WAVE PER ROW. No __syncthreads; per-wave LDS scratch only.
// Gather: lane owns one float2 column; 16 independent 8B loads in flight.
// Assumes K<=64, S+P<=96, D<=128 (lane<nf2 guard).
__global__ __launch_bounds__(256) void row_kernel(
    const float* __restrict__ features,     // [N][D]
    const float* __restrict__ all_logits,   // [N][2]
    const float* __restrict__ center_logits,// [B][2]
    const int*   __restrict__ center_idx,   // [B]
    const int*   __restrict__ neighbor_idx, // [B][K]
    const int*   __restrict__ labels,       // [B]
    const int*   __restrict__ avgp,         // [1]
    const float* __restrict__ sv,           // [Ppool] sorted pool values
    const int*   __restrict__ sg,           // [Ppool] pool feature idx (sorted order)
    float* __restrict__ cat,                // [B][2D]
    int K, int S, int Ppool, int D, int B)
{
    __shared__ int   sel[4][96];   // per-wave: [0,S) neighbors, [S,S+P) positives
    __shared__ float wd[4][96];    // per-wave window distances

    const int t    = threadIdx.x;
    const int lane = t & 63;
    const int wave = t >> 6;
    const int b    = blockIdx.x * 4 + wave;
    if (b >= B) return;                       // no barriers below -> safe

    const float c0  = center_logits[2 * b];
    const int isPos = (labels[b] == 1);
    const int P     = isPos ? (avgp[0] + 1) : 0;
    const int nf2   = D >> 1;                 // 64 for D=128
    const bool act  = lane < nf2;
    const float2* f2 = (const float2*)features;
    float2* cat2 = (float2*)cat;
    const size_t cb2 = (size_t)b * (size_t)(2 * nf2);

    // center row load issued early (overlaps selection work)
    float2 ctr = make_float2(0.f, 0.f);
    if (act) ctr = f2[(size_t)center_idx[b] * nf2 + lane];

    // --- neighbor distance + exact stable rank (top_k tie-break) via shfl ---
    float dv = 3.4e38f;
    int nb = 0;
    if (lane < K) {
        nb = neighbor_idx[(size_t)b * K + lane];
        dv = fabsf(all_logits[2 * nb] - c0);
    }
    int r = 0;
#pragma unroll
    for (int j = 0; j < 64; ++j) {
        float dj = __shfl(dv, j);
        r += (int)((dj < dv) | ((dj == dv) & (j < lane)));
    }
    if (lane < K && r < S) sel[wave][r] = nb;

    // --- positive pool: wave-parallel lower_bound + window rank-select ---
    if (isPos) {
        int cnt = 0;
        for (int j = lane; j < Ppool; j += 64) cnt += (int)(sv[j] < c0);
#pragma unroll
        for (int off = 32; off > 0; off >>= 1) cnt += __shfl_down(cnt, off);
        const int lo = __shfl(cnt, 0);
        int w0 = lo - P; if (w0 < 0) w0 = 0;
        int w1 = lo + P; if (w1 > Ppool) w1 = Ppool;
        const int wsz = w1 - w0;   // <= 2P; contains the P closest (window property)
        for (int i = lane; i < wsz; i += 64) wd[wave][i] = fabsf(sv[w0 + i] - c0);
        // same-wave LDS write->read: compiler inserts lgkmcnt wait; lockstep wave
        for (int i = lane; i < wsz; i += 64) {
            float dvi = wd[wave][i];
            int rr = 0;
            for (int j = 0; j < wsz; ++j) {
                float dj = wd[wave][j];
                rr += (int)((dj < dvi) | ((dj == dvi) & (j < i)));
            }
            if (rr < P) sel[wave][S + rr] = sg[w0 + i];
        }
    }

    // --- gather-sum: lane owns float2 column; 16 independent loads in flight ---
    const int total = S + P;                  // 33 or 66
    float2 acc = make_float2(0.f, 0.f);
    if (act) {
        int i = 0;
        while (i + 16 <= total) {
            float2 x[16];
#pragma unroll
            for (int u = 0; u < 16; ++u)
                x[u] = f2[(size_t)sel[wave][i + u] * nf2 + lane];
#pragma unroll
            for (int u = 0; u < 16; ++u) { acc.x += x[u].x; acc.y += x[u].y; }
            i += 16;
        }
        while (i + 4 <= total) {
            float2 x[4];
#pragma unroll
            for (int u = 0; u < 4; ++u)
                x[u] = f2[(size_t)sel[wave][i + u] * nf2 + lane];
#pragma unroll
            for (int u = 0; u < 4; ++u) { acc.x += x[u].x; acc.y += x[u].y; }
            i += 4;
        }
        for (; i < total; ++i) {
            float2 x = f2[(size_t)sel[wave][i] * nf2 + lane];
            acc.x += x.x; acc.y += x.y;
        }
        const float inv = 1.f / (float)total;
        cat2[cb2 + lane]       = ctr;
        cat2[cb2 + nf2 + lane] = make_float2(acc.x * inv, acc.y * inv);
    }
}

// Kernel 2 (unchanged — est. ~8us, never in top-5):
// out = relu(cat @ W^T + b).  M x Kd @ (128 x Kd)^T -> M x 128.
__global__ __launch_bounds__(256) void gemm_relu_kernel(
    const float* __restrict__ A,    // [M][Kd]
    const float* __restrict__ W,    // [128][Kd]
    const float* __restrict__ bias, // [128]
    float* __restrict__ out,        // [M][128]
    int M, int Kd)
{
    __shared__ __align__(16) float As[32][68];
    __shared__ __align__(16) float Ws[64][132];
    const int t  = threadIdx.x;
    const int m0 = blockIdx.x * 32;
    const int cg = t & 31;
    const int rg = t >> 5;
    float acc[4][4] = {};

    for (int kc = 0; kc < Kd; kc += 64) {
        for (int e = t; e < 512; e += 256) {
            int r = e >> 4, c4 = (e & 15) * 4;
            float4 val = make_float4(0.f, 0.f, 0.f, 0.f);
            int m = m0 + r;
            if (m < M) val = *(const float4*)&A[(size_t)m * Kd + kc + c4];
            *(float4*)&As[r][c4] = val;
        }
        for (int e = t; e < 2048; e += 256) {
            int o = e >> 4, k4 = (e & 15) * 4;
            float4 wv = *(const float4*)&W[(size_t)o * Kd + kc + k4];
            Ws[k4 + 0][o] = wv.x;
            Ws[k4 + 1][o] = wv.y;
            Ws[k4 + 2][o] = wv.z;
            Ws[k4 + 3][o] = wv.w;
        }
        __syncthreads();

        for (int k4 = 0; k4 < 64; k4 += 4) {
            float4 a[4], w[4];
#pragma unroll
            for (int i = 0; i < 4; ++i) a[i] = *(const float4*)&As[rg * 4 + i][k4];
#pragma unroll
            for (int kk = 0; kk < 4; ++kk) w[kk] = *(const float4*)&Ws[k4 + kk][cg * 4];
#pragma unroll
            for (int kk = 0; kk < 4; ++kk) {
#pragma unroll
                for (int i = 0; i < 4; ++i) {
                    float av = ((const float*)&a[i])[kk];
                    acc[i][0] = fmaf(av, w[kk].x, acc[i][0]);
                    acc[i][1] = fmaf(av, w[kk].y, acc[i][1]);
                    acc[i][2] = fmaf(av, w[kk].z, acc[i][2]);
                    acc[i][3] = fmaf(av, w[kk].w, acc[i][3]);
                }
            }
        }
        __syncthreads();
    }

    float4 bv = *(const float4*)&bias[cg * 4];
#pragma unroll
    for (int i = 0; i < 4; ++i) {
        int m = m0 + rg * 4 + i;
        if (m < M) {
            float4 o;
            o.x = fmaxf(acc[i][0] + bv.x, 0.f);
            o.y = fmaxf(acc[i][1] + bv.y, 0.f);
            o.z = fmaxf(acc[i][2] + bv.z, 0.f);
            o.w = fmaxf(acc[i][3] + bv.w, 0.f);
            *(float4*)&out[(size_t)m * 128 + cg * 4] = o;
        }
    }
}

extern "C" void kernel_launch(void* const* d_in, const int* in_sizes, int n_in,
                              void* d_out, int out_size, void* d_ws, size_t ws_size,
                              hipStream_t stream) {
    const float* features      = (const float*)d_in[0];
    const float* all_logits    = (const float*)d_in[1];
    const float* center_logits = (const float*)d_in[2];
    const float* tp_logits     = (const float*)d_in[3];
    const float* W             = (const float*)d_in[4];
    const float* bias          = (const float*)d_in[5];
    const int*   center_idx    = (const int*)d_in[6];
    const int*   neighbor_idx  = (const int*)d_in[7];
    const int*   tp_idx        = (const int*)d_in[8];
    const int*   labels        = (const int*)d_in[9];
    const int*   avgp          = (const int*)d_in[10];

    const int B     = in_sizes[6];
    const int K     = in_sizes[7] / B;
    const int S     = K / 2 + 1;
    const int Ppool = in_sizes[8];
    const int Dout  = in_sizes[5];
    const int D     = in_sizes[4] / (2 * Dout);

    char* ws = (char*)d_ws;
    float* cat  = (float*)ws;                                   // B * 2D f32
    size_t cat_bytes = (size_t)B * 2 * D * sizeof(float);
    float* sv_g = (float*)(ws + cat_bytes);                     // Ppool f32
    int*   sg_g = (int*)(ws + cat_bytes + (size_t)Ppool * 4);   // Ppool i32

    sort_pool_kernel<<<(Ppool + 3) / 4, 256, 0, stream>>>(
        tp_logits, tp_idx, sv_g, sg_g, Ppool);

    row_kernel<<<(B + 3) / 4, 256, 0, stream>>>(
        features, all_logits, center_logits, center_idx, neighbor_idx,
        labels, avgp, sv_g, sg_g, cat, K, S, Ppool, D, B);

    gemm_relu_kernel<<<(B + 31) / 32, 256, 0, stream>>>(
        cat, W, bias, (float*)d_out, B, 2 * D);
}